// Round 1
// baseline (909.566 us; speedup 1.0000x reference)
//
#include <hip/hip_runtime.h>

// Problem constants (from reference)
constexpr int B    = 1024;
constexpr int L    = 50;
constexpr int S    = 256;
constexpr int H    = 4;
constexpr int E    = 64;
constexpr int HID  = 64;
constexpr int SUPP = 10000;

// ---------------------------------------------------------------------------
// Kernel A: user_fea_encode.  One block per batch element.
// NOTE: reference closure-captures src_item_emb for BOTH calls; only the user
// table differs. Softmax here matches the reference exactly: att=0 on padded
// rows, e=exp(att) (no max subtraction), denom = sum(e) + 1e-12.
// ---------------------------------------------------------------------------
__global__ __launch_bounds__(256) void encode_kernel(
    const int* __restrict__ x,            // (B,2)  [:,0]=user_id
    const int* __restrict__ his,          // (B,L)
    const int* __restrict__ hl,           // (B,)
    const float* __restrict__ item_emb,   // src_item_emb (N_ITEM,E) -- always src!
    const float* __restrict__ user_table, // (N_USER,E)
    const float* __restrict__ W_att_w,    // (E,E)
    const float* __restrict__ W_att_b,    // (E,)
    const float* __restrict__ W_agg_w,    // (E,E)
    float* __restrict__ fea_out)          // (B,E)
{
    __shared__ float sW[E * E];
    __shared__ float sWagg[E * E];
    __shared__ float sHist[L * E];
    __shared__ float sU[E];
    __shared__ float sAtt[L];
    __shared__ float sOut[E];

    const int b    = blockIdx.x;
    const int tid  = threadIdx.x;
    const int lane = tid & 63;
    const int wave = tid >> 6;

    for (int i = tid; i < E * E; i += 256) {
        sW[i]    = W_att_w[i];
        sWagg[i] = W_agg_w[i];
    }
    const int uid = x[2 * b];
    if (tid < E) sU[tid] = user_table[uid * E + tid];

    const int hlen = hl[b];
    for (int i = tid; i < L * E; i += 256) {
        const int l = i >> 6;
        const int e = i & 63;
        const int it = his[b * L + l];
        sHist[i] = (l < hlen) ? item_emb[it * E + e] : 0.0f;
    }
    __syncthreads();

    const float bias = W_att_b[lane];
    for (int l = wave; l < L; l += 4) {
        float acc = bias;
        float hsum = sHist[l * E + lane];
#pragma unroll
        for (int i = 0; i < E; i++) {
            acc += sHist[l * E + i] * sW[i * E + lane];
        }
        float part = tanhf(acc) * sU[lane];
#pragma unroll
        for (int off = 32; off; off >>= 1) {
            part += __shfl_xor(part, off);
            hsum += __shfl_xor(hsum, off);
        }
        if (lane == 0) sAtt[l] = (hsum == 0.0f) ? 0.0f : part;
    }
    __syncthreads();

    if (wave == 0) {
        float v = (lane < L) ? expf(sAtt[lane]) : 0.0f;
        float s = v;
#pragma unroll
        for (int off = 32; off; off >>= 1) s += __shfl_xor(s, off);
        const float denom = s + 1e-12f;
        if (lane < L) sAtt[lane] = v / denom;
    }
    __syncthreads();

    if (wave == 0) {
        float acc = 0.0f;
        for (int l = 0; l < L; l++) acc += sAtt[l] * sHist[l * E + lane];
        sOut[lane] = acc;
    }
    __syncthreads();

    if (wave == 0) {
        float acc = 0.0f;
#pragma unroll
        for (int i = 0; i < E; i++) acc += sOut[i] * sWagg[i * E + lane];
        fea_out[b * E + lane] = acc;
    }
}

// ---------------------------------------------------------------------------
// Kernel B: K_supp[h][j][:] = (tgt_user_emb[supp_users[j]]) @ Wk[h]
// Shared by BOTH get_user_emb calls (Wk, supp table identical). This replaces
// the reference's 17.2 GFLOP neigh@Wk with 655 MFLOP.
// ---------------------------------------------------------------------------
__global__ __launch_bounds__(256) void ksupp_kernel(
    const int* __restrict__ supp_users,      // (SUPP,)
    const float* __restrict__ tgt_user_emb,  // (N_USER,E)
    const float* __restrict__ Wk,            // (H,E,E)
    float* __restrict__ K_supp)              // (H,SUPP,E)
{
    __shared__ float sWk[E * E];
    const int h    = blockIdx.y;
    const int tid  = threadIdx.x;
    const int lane = tid & 63;
    const int wave = tid >> 6;

    for (int i = tid; i < E * E; i += 256) sWk[i] = Wk[h * E * E + i];
    __syncthreads();

    const int stride = gridDim.x * 4;
    for (int j = blockIdx.x * 4 + wave; j < SUPP; j += stride) {
        const int u = supp_users[j];
        const float myemb = tgt_user_emb[u * E + lane];
        float acc = 0.0f;
#pragma unroll
        for (int i = 0; i < E; i++) {
            acc += __shfl(myemb, i) * sWk[i * E + lane];
        }
        K_supp[(h * SUPP + j) * E + lane] = acc;
    }
}

// ---------------------------------------------------------------------------
// Kernel Bq: q[call][h][b][:] = fea[b] @ Wq[h]
// ---------------------------------------------------------------------------
__global__ __launch_bounds__(256) void q_kernel(
    const float* __restrict__ fea_src,  // (B,E)
    const float* __restrict__ fea_tgt,  // (B,E)
    const float* __restrict__ Wq,       // (H,E,E)
    float* __restrict__ qout)           // (2,H,B,E)
{
    __shared__ float sWq[E * E];
    const int h    = blockIdx.y;
    const int call = blockIdx.z;
    const int tid  = threadIdx.x;
    const int lane = tid & 63;
    const int wave = tid >> 6;

    for (int i = tid; i < E * E; i += 256) sWq[i] = Wq[h * E * E + i];
    __syncthreads();

    const float* fea = call ? fea_tgt : fea_src;
    const int b0 = blockIdx.x * 16;
    for (int bb = wave; bb < 16; bb += 4) {
        const int b = b0 + bb;
        const float f = fea[b * E + lane];
        float acc = 0.0f;
#pragma unroll
        for (int i = 0; i < E; i++) {
            acc += __shfl(f, i) * sWq[i * E + lane];
        }
        qout[(((call * H) + h) * B + b) * E + lane] = acc;
    }
}

// ---------------------------------------------------------------------------
// Kernel C: attention per (b,h,call). k rows gathered from K_supp, cached in
// LDS for the ctx pass. softmax is jax.nn.softmax (max-subtracted). ctx uses
// k itself (reference quirk); then g = ctx @ Wv[h].
// ---------------------------------------------------------------------------
__global__ __launch_bounds__(256) void attn_kernel(
    const int* __restrict__ sample_idx,  // (2,H,B,S)
    const float* __restrict__ K_supp,    // (H,SUPP,E)
    const float* __restrict__ qarr,      // (2,H,B,E)
    const float* __restrict__ Wv,        // (H,E,E)
    float* __restrict__ gout)            // (2,B,H*E)
{
    __shared__ float sK[S * E];        // 64 KB
    __shared__ float sQ[E];
    __shared__ float sLogit[S];
    __shared__ float sCtxPart[4][E];
    __shared__ float sRed[8];

    const int b    = blockIdx.x;
    const int h    = blockIdx.y;
    const int call = blockIdx.z;
    const int tid  = threadIdx.x;
    const int lane = tid & 63;
    const int wave = tid >> 6;

    if (tid < E) sQ[tid] = qarr[(((call * H) + h) * B + b) * E + tid];
    __syncthreads();

    const int* idx = sample_idx + (((call * H) + h) * B + b) * S;
    const float* Kh = K_supp + (size_t)h * SUPP * E;
    const float q = sQ[lane];

#pragma unroll 4
    for (int s = wave; s < S; s += 4) {
        const int j = idx[s];
        const float kv = Kh[j * E + lane];
        sK[s * E + lane] = kv;
        float p = kv * q;
#pragma unroll
        for (int off = 32; off; off >>= 1) p += __shfl_xor(p, off);
        if (lane == 0) sLogit[s] = p;
    }
    __syncthreads();

    // block softmax over S=256 (one element per thread)
    const float lg = sLogit[tid];
    float m = lg;
#pragma unroll
    for (int off = 32; off; off >>= 1) m = fmaxf(m, __shfl_xor(m, off));
    if (lane == 0) sRed[wave] = m;
    __syncthreads();
    const float mx = fmaxf(fmaxf(sRed[0], sRed[1]), fmaxf(sRed[2], sRed[3]));
    const float ex = expf(lg - mx);
    float sm = ex;
#pragma unroll
    for (int off = 32; off; off >>= 1) sm += __shfl_xor(sm, off);
    if (lane == 0) sRed[4 + wave] = sm;
    __syncthreads();
    const float denom = sRed[4] + sRed[5] + sRed[6] + sRed[7];
    __syncthreads();
    sLogit[tid] = ex / denom;
    __syncthreads();

    // ctx[e] = sum_s attn[s] * k[s][e], split s across waves
    float ctx = 0.0f;
    const int s0 = wave * 64;
    for (int s = s0; s < s0 + 64; s++) {
        ctx += sLogit[s] * sK[s * E + lane];
    }
    sCtxPart[wave][lane] = ctx;
    __syncthreads();

    if (wave == 0) {
        const float c = sCtxPart[0][lane] + sCtxPart[1][lane] +
                        sCtxPart[2][lane] + sCtxPart[3][lane];
        const float* Wvh = Wv + h * E * E;
        float g = 0.0f;
#pragma unroll
        for (int o = 0; o < E; o++) {
            g += __shfl(c, o) * Wvh[o * E + lane];
        }
        gout[((size_t)(call * B) + b) * (H * E) + h * E + lane] = g;
    }
}

// ---------------------------------------------------------------------------
// Kernel D: W_out projection + final MLP + all four outputs.
// out layout: [output(B) | x3(B) | out_emb_s(B*E) | x2(B*E)]
// ---------------------------------------------------------------------------
__global__ __launch_bounds__(256) void final_kernel(
    const int* __restrict__ x,             // (B,2) [:,1]=item_id
    const float* __restrict__ tgt_item_emb,
    const float* __restrict__ gsrc,        // (B, H*E) -> user_emb path
    const float* __restrict__ gtgt,        // (B, H*E) -> hybrid path
    const float* __restrict__ W_out,       // (H*E, E)
    const float* __restrict__ l1_w,        // (2E, HID)
    const float* __restrict__ l1_b,        // (HID,)
    const float* __restrict__ l2_w,        // (HID, E)
    const float* __restrict__ l2_b,        // (E,)
    const float* __restrict__ l3_w,        // (E,1)
    const float* __restrict__ l3_b,        // (1,)
    float* __restrict__ out)
{
    __shared__ float sPart[4][E];
    __shared__ float sHyb[E];
    __shared__ float sItem[E];
    __shared__ float sX1[HID];

    const int b    = blockIdx.x;
    const int tid  = threadIdx.x;
    const int lane = tid & 63;
    const int wave = tid >> 6;

    if (tid < E) {
        const int item = x[2 * b + 1];
        sItem[tid] = tgt_item_emb[item * E + tid];
    }

    // waves 0,1 -> user_emb (gsrc); waves 2,3 -> hybrid (gtgt); split i-range
    const float* grow = (wave < 2) ? (gsrc + (size_t)b * (H * E))
                                   : (gtgt + (size_t)b * (H * E));
    const int i0 = (wave & 1) * 128;
    float acc = 0.0f;
    for (int i = i0; i < i0 + 128; i++) {
        acc += grow[i] * W_out[i * E + lane];
    }
    sPart[wave][lane] = acc;
    __syncthreads();

    if (wave == 0) {
        const float ue = sPart[0][lane] + sPart[1][lane];
        const float prod = ue * sItem[lane];
        out[2 * B + b * E + lane] = prod;  // out_emb_s
        float s = prod;
#pragma unroll
        for (int off = 32; off; off >>= 1) s += __shfl_xor(s, off);
        if (lane == 0) out[b] = s;         // output
    }
    if (wave == 1) {
        sHyb[lane] = sPart[2][lane] + sPart[3][lane];
    }
    __syncthreads();

    if (wave == 0) {
        // x1 = tanh([hybrid, item] @ l1_w + l1_b)
        float a = l1_b[lane];
#pragma unroll
        for (int i = 0; i < E; i++) a += sHyb[i] * l1_w[i * HID + lane];
#pragma unroll
        for (int i = 0; i < E; i++) a += sItem[i] * l1_w[(E + i) * HID + lane];
        sX1[lane] = tanhf(a);
    }
    __syncthreads();

    if (wave == 0) {
        float a = l2_b[lane];
#pragma unroll
        for (int i = 0; i < HID; i++) a += sX1[i] * l2_w[i * E + lane];
        const float x2 = tanhf(a);
        out[2 * B + B * E + b * E + lane] = x2;  // x2_t
        float p = x2 * l3_w[lane];
#pragma unroll
        for (int off = 32; off; off >>= 1) p += __shfl_xor(p, off);
        if (lane == 0) out[B + b] = p + l3_b[0]; // x3_t
    }
}

// ---------------------------------------------------------------------------
extern "C" void kernel_launch(void* const* d_in, const int* in_sizes, int n_in,
                              void* d_out, int out_size, void* d_ws, size_t ws_size,
                              hipStream_t stream) {
    const int*   x            = (const int*)d_in[0];
    const int*   src_his      = (const int*)d_in[1];
    const int*   src_hl       = (const int*)d_in[2];
    const int*   tgt_his      = (const int*)d_in[3];
    const int*   tgt_hl       = (const int*)d_in[4];
    const int*   sample_idx   = (const int*)d_in[5];
    const int*   supp_users   = (const int*)d_in[6];
    const float* src_user_emb = (const float*)d_in[7];
    const float* src_item_emb = (const float*)d_in[8];
    const float* tgt_user_emb = (const float*)d_in[9];
    const float* tgt_item_emb = (const float*)d_in[10];
    const float* W_att_w      = (const float*)d_in[11];
    const float* W_att_b      = (const float*)d_in[12];
    const float* W_agg_w      = (const float*)d_in[13];
    const float* Wq           = (const float*)d_in[14];
    const float* Wk           = (const float*)d_in[15];
    const float* Wv           = (const float*)d_in[16];
    const float* W_out        = (const float*)d_in[17];
    const float* l1_w         = (const float*)d_in[18];
    const float* l1_b         = (const float*)d_in[19];
    const float* l2_w         = (const float*)d_in[20];
    const float* l2_b         = (const float*)d_in[21];
    const float* l3_w         = (const float*)d_in[22];
    const float* l3_b         = (const float*)d_in[23];

    float* ws      = (float*)d_ws;
    float* fea_src = ws;                                  // B*E
    float* fea_tgt = fea_src + B * E;                     // B*E
    float* qarr    = fea_tgt + B * E;                     // 2*H*B*E
    float* K_supp  = qarr + 2 * H * B * E;                // H*SUPP*E
    float* garr    = K_supp + H * SUPP * E;               // 2*B*H*E
    float* out     = (float*)d_out;

    encode_kernel<<<dim3(B), 256, 0, stream>>>(
        x, src_his, src_hl, src_item_emb, src_user_emb,
        W_att_w, W_att_b, W_agg_w, fea_src);
    encode_kernel<<<dim3(B), 256, 0, stream>>>(
        x, tgt_his, tgt_hl, src_item_emb, tgt_user_emb,
        W_att_w, W_att_b, W_agg_w, fea_tgt);
    ksupp_kernel<<<dim3(40, H), 256, 0, stream>>>(
        supp_users, tgt_user_emb, Wk, K_supp);
    q_kernel<<<dim3(B / 16, H, 2), 256, 0, stream>>>(
        fea_src, fea_tgt, Wq, qarr);
    attn_kernel<<<dim3(B, H, 2), 256, 0, stream>>>(
        sample_idx, K_supp, qarr, Wv, garr);
    final_kernel<<<dim3(B), 256, 0, stream>>>(
        x, tgt_item_emb, garr, garr + B * H * E, W_out,
        l1_w, l1_b, l2_w, l2_b, l3_w, l3_b, out);
}

// Round 2
// 373.877 us; speedup vs baseline: 2.4328x; 2.4328x over previous
//
#include <hip/hip_runtime.h>

// Problem constants (from reference)
constexpr int B    = 1024;
constexpr int L    = 50;
constexpr int S    = 256;
constexpr int H    = 4;
constexpr int E    = 64;
constexpr int HID  = 64;
constexpr int SUPP = 10000;

// Broadcast lane l's value to all lanes of the wave (l must be uniform/constant;
// compiles to v_readlane -> SGPR, usable as the scalar operand of v_fma).
__device__ __forceinline__ float lanebc(float v, int l) {
    return __int_as_float(__builtin_amdgcn_readlane(__float_as_int(v), l));
}

// ---------------------------------------------------------------------------
// Kernel A: user_fea_encode.  One block (256 thr) per batch element.
// Reference quirks preserved: src_item_emb for BOTH calls; encoder softmax has
// no max-subtract, padded rows contribute exp(0)=1; denom = sum + 1e-12.
// ---------------------------------------------------------------------------
__global__ __launch_bounds__(256) void encode_kernel(
    const int* __restrict__ x,            // (B,2)  [:,0]=user_id
    const int* __restrict__ his,          // (B,L)
    const int* __restrict__ hl,           // (B,)
    const float* __restrict__ item_emb,   // src_item_emb (N_ITEM,E) -- always src!
    const float* __restrict__ user_table, // (N_USER,E)
    const float* __restrict__ W_att_w,    // (E,E)
    const float* __restrict__ W_att_b,    // (E,)
    const float* __restrict__ W_agg_w,    // (E,E)
    float* __restrict__ fea_out)          // (B,E)
{
    __shared__ float sW[E * E];
    __shared__ float sWagg[E * E];
    __shared__ float sHist[L * E];
    __shared__ float sU[E];
    __shared__ float sAtt[L];
    __shared__ float sPart[4][E];
    __shared__ float sOut[E];

    const int b    = blockIdx.x;
    const int tid  = threadIdx.x;
    const int lane = tid & 63;
    const int wave = tid >> 6;

    for (int i = tid; i < E * E; i += 256) {
        sW[i]    = W_att_w[i];
        sWagg[i] = W_agg_w[i];
    }
    const int uid = x[2 * b];
    if (tid < E) sU[tid] = user_table[uid * E + tid];

    const int hlen = hl[b];
    for (int i = tid; i < L * E; i += 256) {
        const int l = i >> 6;
        const int e = i & 63;
        const int it = his[b * L + l];
        sHist[i] = (l < hlen) ? item_emb[it * E + e] : 0.0f;
    }
    __syncthreads();

    const float bias = W_att_b[lane];
    for (int l = wave; l < L; l += 4) {
        const float hv = sHist[l * E + lane];
        float a = bias;
#pragma unroll
        for (int i = 0; i < E; i++) {
            a += lanebc(hv, i) * sW[i * E + lane];
        }
        float part = tanhf(a) * sU[lane];
        float hsum = hv;
#pragma unroll
        for (int off = 32; off; off >>= 1) {
            part += __shfl_xor(part, off);
            hsum += __shfl_xor(hsum, off);
        }
        if (lane == 0) sAtt[l] = (hsum == 0.0f) ? 0.0f : part;
    }
    __syncthreads();

    if (wave == 0) {
        float v = (lane < L) ? expf(sAtt[lane]) : 0.0f;
        float s = v;
#pragma unroll
        for (int off = 32; off; off >>= 1) s += __shfl_xor(s, off);
        const float denom = s + 1e-12f;
        if (lane < L) sAtt[lane] = v / denom;
    }
    __syncthreads();

    // ctx partials across waves
    float c = 0.0f;
    for (int l = wave; l < L; l += 4) c += sAtt[l] * sHist[l * E + lane];
    sPart[wave][lane] = c;
    __syncthreads();
    if (tid < E) sOut[tid] = sPart[0][tid] + sPart[1][tid] + sPart[2][tid] + sPart[3][tid];
    __syncthreads();

    // agg: out = ctx @ W_agg, i-range split across waves
    float g = 0.0f;
#pragma unroll
    for (int k = 0; k < 16; k++) {
        const int i = wave * 16 + k;
        g += sOut[i] * sWagg[i * E + lane];
    }
    sPart[wave][lane] = g;
    __syncthreads();
    if (wave == 0) {
        fea_out[b * E + lane] =
            sPart[0][lane] + sPart[1][lane] + sPart[2][lane] + sPart[3][lane];
    }
}

// ---------------------------------------------------------------------------
// Kernel B: K_supp[h][j][:] = (tgt_user_emb[supp_users[j]]) @ Wk[h]
// wave <-> head; Wk column held in 64 VGPRs; zero LDS in inner loop.
// ---------------------------------------------------------------------------
__global__ __launch_bounds__(256) void ksupp_kernel(
    const int* __restrict__ supp_users,      // (SUPP,)
    const float* __restrict__ tgt_user_emb,  // (N_USER,E)
    const float* __restrict__ Wk,            // (H,E,E)
    float* __restrict__ K_supp)              // (H,SUPP,E)
{
    const int tid  = threadIdx.x;
    const int lane = tid & 63;
    const int h    = tid >> 6;   // wave == head

    float wcol[E];
#pragma unroll
    for (int i = 0; i < E; i++) wcol[i] = Wk[h * E * E + i * E + lane];

    for (int j = blockIdx.x; j < SUPP; j += gridDim.x) {
        const int u = supp_users[j];
        const float ev = tgt_user_emb[(size_t)u * E + lane];
        float acc = 0.0f;
#pragma unroll
        for (int i = 0; i < E; i++) acc += lanebc(ev, i) * wcol[i];
        K_supp[((size_t)h * SUPP + j) * E + lane] = acc;
    }
}

// ---------------------------------------------------------------------------
// Kernel Bq: q[call][h][b][:] = fea[b] @ Wq[h].  wave <-> head.
// ---------------------------------------------------------------------------
__global__ __launch_bounds__(256) void q_kernel(
    const float* __restrict__ fea_src,  // (B,E)
    const float* __restrict__ fea_tgt,  // (B,E)
    const float* __restrict__ Wq,       // (H,E,E)
    float* __restrict__ qout)           // (2,H,B,E)
{
    const int tid  = threadIdx.x;
    const int lane = tid & 63;
    const int h    = tid >> 6;
    const int call = blockIdx.y;

    float wcol[E];
#pragma unroll
    for (int i = 0; i < E; i++) wcol[i] = Wq[h * E * E + i * E + lane];

    const float* fea = call ? fea_tgt : fea_src;
    for (int b = blockIdx.x; b < B; b += gridDim.x) {
        const float fv = fea[b * E + lane];
        float acc = 0.0f;
#pragma unroll
        for (int i = 0; i < E; i++) acc += lanebc(fv, i) * wcol[i];
        qout[(((call * H) + h) * B + b) * E + lane] = acc;
    }
}

// ---------------------------------------------------------------------------
// Kernel C: attention per (b,h,call).  K rows gathered into XOR-swizzled LDS
// (word = s*64 + (e ^ ((s>>1)&31)) -- conflict-free for row-writes,
// per-thread row reads, and per-column ctx reads).  Logits: one per thread,
// no shuffle chains.  softmax = jax.nn.softmax (max-subtracted).  ctx uses k
// itself (reference quirk); g = ctx @ Wv[h].
// ---------------------------------------------------------------------------
__global__ __launch_bounds__(256) void attn_kernel(
    const int* __restrict__ sample_idx,  // (2,H,B,S)
    const float* __restrict__ K_supp,    // (H,SUPP,E)
    const float* __restrict__ qarr,      // (2,H,B,E)
    const float* __restrict__ Wv,        // (H,E,E)
    float* __restrict__ gout)            // (2,B,H*E)
{
    __shared__ float sK[S * E];          // 64 KB, swizzled
    __shared__ float sRed[8];
    __shared__ float sCtx[4][E];
    __shared__ float sC[E];
    __shared__ float sG[4][E];

    const int b    = blockIdx.x;
    const int h    = blockIdx.y;
    const int call = blockIdx.z;
    const int tid  = threadIdx.x;
    const int lane = tid & 63;
    const int wave = tid >> 6;

    const int* idx = sample_idx + (((call * H) + h) * B + b) * S;
    const float* Kh = K_supp + (size_t)h * SUPP * E;
    const float qv = qarr[(((call * H) + h) * B + b) * E + lane];  // q[lane]

    // ---- gather: wave w stages rows s in [w*64, (w+1)*64) ----
    const int s0 = wave * 64;
    const int idxv = idx[s0 + lane];
#pragma unroll
    for (int i = 0; i < 64; i++) {
        const int s = s0 + i;
        const int j = __builtin_amdgcn_readlane(idxv, i);
        sK[s * 64 + (lane ^ ((s >> 1) & 31))] = Kh[(size_t)j * E + lane];
    }
    __syncthreads();

    // ---- logits: thread t computes logit for row s=t ----
    const int swz = (tid >> 1) & 31;
    const float* rowp = sK + tid * 64;
    float acc = 0.0f;
#pragma unroll
    for (int e = 0; e < 32; e++) {
        const int xo = e ^ swz;
        acc += rowp[xo]      * lanebc(qv, e);
        acc += rowp[xo + 32] * lanebc(qv, e + 32);
    }

    // ---- block softmax over 256 logits ----
    float m = acc;
#pragma unroll
    for (int off = 32; off; off >>= 1) m = fmaxf(m, __shfl_xor(m, off));
    if (lane == 0) sRed[wave] = m;
    __syncthreads();
    const float mx = fmaxf(fmaxf(sRed[0], sRed[1]), fmaxf(sRed[2], sRed[3]));
    const float ex = expf(acc - mx);
    float sm = ex;
#pragma unroll
    for (int off = 32; off; off >>= 1) sm += __shfl_xor(sm, off);
    if (lane == 0) sRed[4 + wave] = sm;
    __syncthreads();
    const float denom = sRed[4] + sRed[5] + sRed[6] + sRed[7];
    const float pval = ex / denom;   // attn weight for s = tid

    // ---- ctx: wave w owns s in [w*64, (w+1)*64); its own lanes hold p ----
    float ctx = 0.0f;
#pragma unroll
    for (int i = 0; i < 64; i += 2) {
        const int s = s0 + i;
        const int sw2 = (s >> 1) & 31;   // same for s and s+1
        const float p0 = lanebc(pval, i);
        const float p1 = lanebc(pval, i + 1);
        ctx += p0 * sK[s * 64 + (lane ^ sw2)];
        ctx += p1 * sK[(s + 1) * 64 + (lane ^ sw2)];
    }
    sCtx[wave][lane] = ctx;
    __syncthreads();
    if (wave == 0) {
        sC[lane] = sCtx[0][lane] + sCtx[1][lane] + sCtx[2][lane] + sCtx[3][lane];
    }
    __syncthreads();

    // ---- g = ctx @ Wv[h], c-range split across waves ----
    const float* Wvh = Wv + h * E * E;
    float g = 0.0f;
#pragma unroll
    for (int k = 0; k < 16; k++) {
        const int c = wave * 16 + k;
        g += sC[c] * Wvh[c * E + lane];
    }
    sG[wave][lane] = g;
    __syncthreads();
    if (wave == 0) {
        gout[((size_t)(call * B) + b) * (H * E) + h * E + lane] =
            sG[0][lane] + sG[1][lane] + sG[2][lane] + sG[3][lane];
    }
}

// ---------------------------------------------------------------------------
// Kernel D: W_out projection + final MLP + all four outputs.
// out layout: [output(B) | x3(B) | out_emb_s(B*E) | x2(B*E)]
// ---------------------------------------------------------------------------
__global__ __launch_bounds__(256) void final_kernel(
    const int* __restrict__ x,             // (B,2) [:,1]=item_id
    const float* __restrict__ tgt_item_emb,
    const float* __restrict__ gsrc,        // (B, H*E) -> user_emb path
    const float* __restrict__ gtgt,        // (B, H*E) -> hybrid path
    const float* __restrict__ W_out,       // (H*E, E)
    const float* __restrict__ l1_w,        // (2E, HID)
    const float* __restrict__ l1_b,        // (HID,)
    const float* __restrict__ l2_w,        // (HID, E)
    const float* __restrict__ l2_b,        // (E,)
    const float* __restrict__ l3_w,        // (E,1)
    const float* __restrict__ l3_b,        // (1,)
    float* __restrict__ out)
{
    __shared__ float sPart[4][E];
    __shared__ float sHyb[E];
    __shared__ float sItem[E];
    __shared__ float sX1[HID];

    const int b    = blockIdx.x;
    const int tid  = threadIdx.x;
    const int lane = tid & 63;
    const int wave = tid >> 6;

    if (tid < E) {
        const int item = x[2 * b + 1];
        sItem[tid] = tgt_item_emb[item * E + tid];
    }

    const float* grow = (wave < 2) ? (gsrc + (size_t)b * (H * E))
                                   : (gtgt + (size_t)b * (H * E));
    const int i0 = (wave & 1) * 128;
    float acc = 0.0f;
    for (int i = i0; i < i0 + 128; i++) {
        acc += grow[i] * W_out[i * E + lane];
    }
    sPart[wave][lane] = acc;
    __syncthreads();

    if (wave == 0) {
        const float ue = sPart[0][lane] + sPart[1][lane];
        const float prod = ue * sItem[lane];
        out[2 * B + b * E + lane] = prod;  // out_emb_s
        float s = prod;
#pragma unroll
        for (int off = 32; off; off >>= 1) s += __shfl_xor(s, off);
        if (lane == 0) out[b] = s;         // output
    }
    if (wave == 1) {
        sHyb[lane] = sPart[2][lane] + sPart[3][lane];
    }
    __syncthreads();

    if (wave == 0) {
        float a = l1_b[lane];
#pragma unroll
        for (int i = 0; i < E; i++) a += sHyb[i] * l1_w[i * HID + lane];
#pragma unroll
        for (int i = 0; i < E; i++) a += sItem[i] * l1_w[(E + i) * HID + lane];
        sX1[lane] = tanhf(a);
    }
    __syncthreads();

    if (wave == 0) {
        float a = l2_b[lane];
#pragma unroll
        for (int i = 0; i < HID; i++) a += sX1[i] * l2_w[i * E + lane];
        const float x2 = tanhf(a);
        out[2 * B + B * E + b * E + lane] = x2;  // x2_t
        float p = x2 * l3_w[lane];
#pragma unroll
        for (int off = 32; off; off >>= 1) p += __shfl_xor(p, off);
        if (lane == 0) out[B + b] = p + l3_b[0]; // x3_t
    }
}

// ---------------------------------------------------------------------------
extern "C" void kernel_launch(void* const* d_in, const int* in_sizes, int n_in,
                              void* d_out, int out_size, void* d_ws, size_t ws_size,
                              hipStream_t stream) {
    const int*   x            = (const int*)d_in[0];
    const int*   src_his      = (const int*)d_in[1];
    const int*   src_hl       = (const int*)d_in[2];
    const int*   tgt_his      = (const int*)d_in[3];
    const int*   tgt_hl       = (const int*)d_in[4];
    const int*   sample_idx   = (const int*)d_in[5];
    const int*   supp_users   = (const int*)d_in[6];
    const float* src_user_emb = (const float*)d_in[7];
    const float* src_item_emb = (const float*)d_in[8];
    const float* tgt_user_emb = (const float*)d_in[9];
    const float* tgt_item_emb = (const float*)d_in[10];
    const float* W_att_w      = (const float*)d_in[11];
    const float* W_att_b      = (const float*)d_in[12];
    const float* W_agg_w      = (const float*)d_in[13];
    const float* Wq           = (const float*)d_in[14];
    const float* Wk           = (const float*)d_in[15];
    const float* Wv           = (const float*)d_in[16];
    const float* W_out        = (const float*)d_in[17];
    const float* l1_w         = (const float*)d_in[18];
    const float* l1_b         = (const float*)d_in[19];
    const float* l2_w         = (const float*)d_in[20];
    const float* l2_b         = (const float*)d_in[21];
    const float* l3_w         = (const float*)d_in[22];
    const float* l3_b         = (const float*)d_in[23];

    float* ws      = (float*)d_ws;
    float* fea_src = ws;                                  // B*E
    float* fea_tgt = fea_src + B * E;                     // B*E
    float* qarr    = fea_tgt + B * E;                     // 2*H*B*E
    float* K_supp  = qarr + 2 * H * B * E;                // H*SUPP*E
    float* garr    = K_supp + H * SUPP * E;               // 2*B*H*E
    float* out     = (float*)d_out;

    encode_kernel<<<dim3(B), 256, 0, stream>>>(
        x, src_his, src_hl, src_item_emb, src_user_emb,
        W_att_w, W_att_b, W_agg_w, fea_src);
    encode_kernel<<<dim3(B), 256, 0, stream>>>(
        x, tgt_his, tgt_hl, src_item_emb, tgt_user_emb,
        W_att_w, W_att_b, W_agg_w, fea_tgt);
    ksupp_kernel<<<dim3(256), 256, 0, stream>>>(
        supp_users, tgt_user_emb, Wk, K_supp);
    q_kernel<<<dim3(64, 2), 256, 0, stream>>>(
        fea_src, fea_tgt, Wq, qarr);
    attn_kernel<<<dim3(B, H, 2), 256, 0, stream>>>(
        sample_idx, K_supp, qarr, Wv, garr);
    final_kernel<<<dim3(B), 256, 0, stream>>>(
        x, tgt_item_emb, garr, garr + B * H * E, W_out,
        l1_w, l1_b, l2_w, l2_b, l3_w, l3_b, out);
}

// Round 3
// 304.173 us; speedup vs baseline: 2.9903x; 1.2292x over previous
//
#include <hip/hip_runtime.h>

// Problem constants (from reference)
constexpr int B    = 1024;
constexpr int L    = 50;
constexpr int S    = 256;
constexpr int H    = 4;
constexpr int E    = 64;
constexpr int HID  = 64;
constexpr int SUPP = 10000;

// Broadcast lane l's value to all lanes of the wave (l must be wave-uniform;
// compiles to v_readlane -> SGPR, usable as the scalar operand of v_fma).
__device__ __forceinline__ float lanebc(float v, int l) {
    return __int_as_float(__builtin_amdgcn_readlane(__float_as_int(v), l));
}

// ---------------------------------------------------------------------------
// Kernel A: user_fea_encode for BOTH calls (blockIdx.y = call).
// Reference quirks preserved: src_item_emb for BOTH calls; encoder softmax has
// no max-subtract, padded rows contribute exp(0)=1; denom = sum + 1e-12.
// W_att column lives in 64 VGPRs -> inner matmul loop is pure VALU.
// ---------------------------------------------------------------------------
__global__ __launch_bounds__(256) void encode_kernel(
    const int* __restrict__ x,            // (B,2)  [:,0]=user_id
    const int* __restrict__ src_his,      // (B,L)
    const int* __restrict__ src_hl,       // (B,)
    const int* __restrict__ tgt_his,      // (B,L)
    const int* __restrict__ tgt_hl,       // (B,)
    const float* __restrict__ item_emb,   // src_item_emb (N_ITEM,E) -- always src!
    const float* __restrict__ src_user_emb,
    const float* __restrict__ tgt_user_emb,
    const float* __restrict__ W_att_w,    // (E,E)
    const float* __restrict__ W_att_b,    // (E,)
    const float* __restrict__ W_agg_w,    // (E,E)
    float* __restrict__ fea_out)          // (2,B,E)
{
    __shared__ float sHist[L * E];
    __shared__ float sAtt[L];
    __shared__ float sPart[4][E];
    __shared__ float sOut[E];

    const int b    = blockIdx.x;
    const int call = blockIdx.y;
    const int tid  = threadIdx.x;
    const int lane = tid & 63;
    const int wave = tid >> 6;

    const int* his = call ? tgt_his : src_his;
    const int* hl  = call ? tgt_hl  : src_hl;
    const float* user_table = call ? tgt_user_emb : src_user_emb;

    // W_att column in VGPRs
    float wcol[E];
#pragma unroll
    for (int i = 0; i < E; i++) wcol[i] = W_att_w[i * E + lane];

    const int uid   = x[2 * b];
    const float uv  = user_table[(size_t)uid * E + lane];
    const float bias = W_att_b[lane];
    const int hlen  = hl[b];

    // phase 1: per history row -- gather, stage, key-matmul, att logit
    for (int l = wave; l < L; l += 4) {
        const int it = his[b * L + l];
        const float hv = (l < hlen) ? item_emb[(size_t)it * E + lane] : 0.0f;
        sHist[l * E + lane] = hv;
        float a = bias;
#pragma unroll
        for (int i = 0; i < E; i++) a += lanebc(hv, i) * wcol[i];
        float part = tanhf(a) * uv;
        float hsum = hv;
#pragma unroll
        for (int off = 32; off; off >>= 1) {
            part += __shfl_xor(part, off);
            hsum += __shfl_xor(hsum, off);
        }
        if (lane == 0) sAtt[l] = (hsum == 0.0f) ? 0.0f : part;
    }
    __syncthreads();

    // softmax (no max-subtract, padded rows contribute exp(0)=1)
    if (wave == 0) {
        float v = (lane < L) ? expf(sAtt[lane]) : 0.0f;
        float s = v;
#pragma unroll
        for (int off = 32; off; off >>= 1) s += __shfl_xor(s, off);
        const float denom = s + 1e-12f;
        if (lane < L) sAtt[lane] = v / denom;
    }
    __syncthreads();

    // ctx partials across waves
    float c = 0.0f;
    for (int l = wave; l < L; l += 4) c += sAtt[l] * sHist[l * E + lane];
    sPart[wave][lane] = c;
    __syncthreads();
    if (tid < E) sOut[tid] = sPart[0][tid] + sPart[1][tid] + sPart[2][tid] + sPart[3][tid];
    __syncthreads();

    // agg: out = ctx @ W_agg, i-range split across waves (W_agg from global/L2)
    float g = 0.0f;
#pragma unroll
    for (int k = 0; k < 16; k++) {
        const int i = wave * 16 + k;
        g += sOut[i] * W_agg_w[i * E + lane];
    }
    sPart[wave][lane] = g;
    __syncthreads();
    if (wave == 0) {
        fea_out[((size_t)call * B + b) * E + lane] =
            sPart[0][lane] + sPart[1][lane] + sPart[2][lane] + sPart[3][lane];
    }
}

// ---------------------------------------------------------------------------
// Kernel B: K_supp[h][j][:] = (tgt_user_emb[supp_users[j]]) @ Wk[h]
// wave <-> head; Wk column held in 64 VGPRs; zero LDS.
// ---------------------------------------------------------------------------
__global__ __launch_bounds__(256) void ksupp_kernel(
    const int* __restrict__ supp_users,      // (SUPP,)
    const float* __restrict__ tgt_user_emb,  // (N_USER,E)
    const float* __restrict__ Wk,            // (H,E,E)
    float* __restrict__ K_supp)              // (H,SUPP,E)
{
    const int tid  = threadIdx.x;
    const int lane = tid & 63;
    const int h    = tid >> 6;   // wave == head

    float wcol[E];
#pragma unroll
    for (int i = 0; i < E; i++) wcol[i] = Wk[h * E * E + i * E + lane];

#pragma unroll 2
    for (int j = blockIdx.x; j < SUPP; j += gridDim.x) {
        const int u = supp_users[j];
        const float ev = tgt_user_emb[(size_t)u * E + lane];
        float acc = 0.0f;
#pragma unroll
        for (int i = 0; i < E; i++) acc += lanebc(ev, i) * wcol[i];
        K_supp[((size_t)h * SUPP + j) * E + lane] = acc;
    }
}

// ---------------------------------------------------------------------------
// Kernel Bq: q[call][h][b][:] = fea[b] @ Wq[h].  wave <-> head.
// ---------------------------------------------------------------------------
__global__ __launch_bounds__(256) void q_kernel(
    const float* __restrict__ fea,      // (2,B,E)
    const float* __restrict__ Wq,       // (H,E,E)
    float* __restrict__ qout)           // (2,H,B,E)
{
    const int tid  = threadIdx.x;
    const int lane = tid & 63;
    const int h    = tid >> 6;
    const int call = blockIdx.y;

    float wcol[E];
#pragma unroll
    for (int i = 0; i < E; i++) wcol[i] = Wq[h * E * E + i * E + lane];

    for (int b = blockIdx.x; b < B; b += gridDim.x) {
        const float fv = fea[((size_t)call * B + b) * E + lane];
        float acc = 0.0f;
#pragma unroll
        for (int i = 0; i < E; i++) acc += lanebc(fv, i) * wcol[i];
        qout[(((call * H) + h) * B + b) * E + lane] = acc;
    }
}

// ---------------------------------------------------------------------------
// Kernel C: attention per (b,h,call).  K rows gathered to LDS via dwordx4 with
// a unit-level XOR swizzle: logical unit u (4 floats) of row s is stored at
// position u^(s&15).  All phases iterate over LOGICAL unit (wave-uniform) so
// q-broadcast indices stay uniform.  softmax = jax.nn.softmax (max-subtract).
// ctx uses k itself (reference quirk); g = ctx @ Wv[h].
// ---------------------------------------------------------------------------
__global__ __launch_bounds__(256) void attn_kernel(
    const int* __restrict__ sample_idx,  // (2,H,B,S)
    const float* __restrict__ K_supp,    // (H,SUPP,E)
    const float* __restrict__ qarr,      // (2,H,B,E)
    const float* __restrict__ Wv,        // (H,E,E)
    float* __restrict__ gout)            // (2,B,H*E)
{
    __shared__ float sK[S * E];          // 64 KB, unit-swizzled
    __shared__ float sP[S];
    __shared__ float sRed[8];
    __shared__ float sCtx[4][E];
    __shared__ float sC[E];
    __shared__ float sG[4][E];

    const int b    = blockIdx.x;
    const int h    = blockIdx.y;
    const int call = blockIdx.z;
    const int tid  = threadIdx.x;
    const int lane = tid & 63;
    const int wave = tid >> 6;

    const int* idx = sample_idx + (((call * H) + h) * B + b) * S;
    const float* Kh = K_supp + (size_t)h * SUPP * E;
    const float qv = qarr[(((call * H) + h) * B + b) * E + lane];  // q[lane]

    // ---- gather: wave w stages rows [w*64,(w+1)*64), 4 rows per iteration ----
    const int s0   = wave * 64;
    const int u    = lane & 15;   // logical unit (4 floats)
    const int rsub = lane >> 4;   // row within 4-row group
#pragma unroll
    for (int i = 0; i < 16; i++) {
        const int r = s0 + i * 4 + rsub;
        const int j = idx[r];     // 16 lanes same address (L1 broadcast)
        const float4 kv = *(const float4*)(Kh + (size_t)j * E + u * 4);
        *(float4*)(sK + r * 64 + ((u ^ (r & 15)) << 2)) = kv;
    }
    __syncthreads();

    // ---- logits: thread t computes logit for row s=t (16 b128 reads) ----
    const int tmask = tid & 15;
    float acc = 0.0f;
#pragma unroll
    for (int uu = 0; uu < 16; uu++) {
        const float4 kv = *(const float4*)(sK + tid * 64 + (((uu ^ tmask)) << 2));
        acc += kv.x * lanebc(qv, 4 * uu)
             + kv.y * lanebc(qv, 4 * uu + 1)
             + kv.z * lanebc(qv, 4 * uu + 2)
             + kv.w * lanebc(qv, 4 * uu + 3);
    }

    // ---- block softmax over 256 logits ----
    float m = acc;
#pragma unroll
    for (int off = 32; off; off >>= 1) m = fmaxf(m, __shfl_xor(m, off));
    if (lane == 0) sRed[wave] = m;
    __syncthreads();
    const float mx = fmaxf(fmaxf(sRed[0], sRed[1]), fmaxf(sRed[2], sRed[3]));
    const float ex = expf(acc - mx);
    float sm = ex;
#pragma unroll
    for (int off = 32; off; off >>= 1) sm += __shfl_xor(sm, off);
    if (lane == 0) sRed[4 + wave] = sm;
    __syncthreads();
    const float denom = sRed[4] + sRed[5] + sRed[6] + sRed[7];
    sP[tid] = ex / denom;   // attn weight for s = tid
    __syncthreads();

    // ---- ctx: wave w sums its 64 rows.  lane = (quarter, unit): 16 b128 ----
    float4 cacc = make_float4(0.0f, 0.0f, 0.0f, 0.0f);
    const int sbase = s0 + (lane >> 4) * 16;
#pragma unroll
    for (int i = 0; i < 16; i++) {
        const int s = sbase + i;
        const float ps = sP[s];
        const float4 kv = *(const float4*)(sK + s * 64 + ((u ^ (s & 15)) << 2));
        cacc.x += ps * kv.x;
        cacc.y += ps * kv.y;
        cacc.z += ps * kv.z;
        cacc.w += ps * kv.w;
    }
    // combine quarters (lanes l, l^16, l^32, l^48 hold same unit)
#pragma unroll
    for (int off = 16; off <= 32; off <<= 1) {
        cacc.x += __shfl_xor(cacc.x, off);
        cacc.y += __shfl_xor(cacc.y, off);
        cacc.z += __shfl_xor(cacc.z, off);
        cacc.w += __shfl_xor(cacc.w, off);
    }
    if (lane < 16) *(float4*)(&sCtx[wave][u * 4]) = cacc;
    __syncthreads();
    if (wave == 0) {
        sC[lane] = sCtx[0][lane] + sCtx[1][lane] + sCtx[2][lane] + sCtx[3][lane];
    }
    __syncthreads();

    // ---- g = ctx @ Wv[h], c-range split across waves ----
    const float* Wvh = Wv + h * E * E;
    float g = 0.0f;
#pragma unroll
    for (int k = 0; k < 16; k++) {
        const int c = wave * 16 + k;
        g += sC[c] * Wvh[c * E + lane];
    }
    sG[wave][lane] = g;
    __syncthreads();
    if (wave == 0) {
        gout[((size_t)(call * B) + b) * (H * E) + h * E + lane] =
            sG[0][lane] + sG[1][lane] + sG[2][lane] + sG[3][lane];
    }
}

// ---------------------------------------------------------------------------
// Kernel D: W_out projection + final MLP + all four outputs.
// out layout: [output(B) | x3(B) | out_emb_s(B*E) | x2(B*E)]
// ---------------------------------------------------------------------------
__global__ __launch_bounds__(256) void final_kernel(
    const int* __restrict__ x,             // (B,2) [:,1]=item_id
    const float* __restrict__ tgt_item_emb,
    const float* __restrict__ gsrc,        // (B, H*E) -> user_emb path
    const float* __restrict__ gtgt,        // (B, H*E) -> hybrid path
    const float* __restrict__ W_out,       // (H*E, E)
    const float* __restrict__ l1_w,        // (2E, HID)
    const float* __restrict__ l1_b,        // (HID,)
    const float* __restrict__ l2_w,        // (HID, E)
    const float* __restrict__ l2_b,        // (E,)
    const float* __restrict__ l3_w,        // (E,1)
    const float* __restrict__ l3_b,        // (1,)
    float* __restrict__ out)
{
    __shared__ float sPart[4][E];
    __shared__ float sHyb[E];
    __shared__ float sItem[E];
    __shared__ float sX1[HID];

    const int b    = blockIdx.x;
    const int tid  = threadIdx.x;
    const int lane = tid & 63;
    const int wave = tid >> 6;

    if (tid < E) {
        const int item = x[2 * b + 1];
        sItem[tid] = tgt_item_emb[(size_t)item * E + tid];
    }

    const float* grow = (wave < 2) ? (gsrc + (size_t)b * (H * E))
                                   : (gtgt + (size_t)b * (H * E));
    const int i0 = (wave & 1) * 128;
    float acc = 0.0f;
    for (int i = i0; i < i0 + 128; i++) {
        acc += grow[i] * W_out[i * E + lane];
    }
    sPart[wave][lane] = acc;
    __syncthreads();

    if (wave == 0) {
        const float ue = sPart[0][lane] + sPart[1][lane];
        const float prod = ue * sItem[lane];
        out[2 * B + b * E + lane] = prod;  // out_emb_s
        float s = prod;
#pragma unroll
        for (int off = 32; off; off >>= 1) s += __shfl_xor(s, off);
        if (lane == 0) out[b] = s;         // output
    }
    if (wave == 1) {
        sHyb[lane] = sPart[2][lane] + sPart[3][lane];
    }
    __syncthreads();

    if (wave == 0) {
        float a = l1_b[lane];
#pragma unroll
        for (int i = 0; i < E; i++) a += sHyb[i] * l1_w[i * HID + lane];
#pragma unroll
        for (int i = 0; i < E; i++) a += sItem[i] * l1_w[(E + i) * HID + lane];
        sX1[lane] = tanhf(a);
    }
    __syncthreads();

    if (wave == 0) {
        float a = l2_b[lane];
#pragma unroll
        for (int i = 0; i < HID; i++) a += sX1[i] * l2_w[i * E + lane];
        const float x2 = tanhf(a);
        out[2 * B + B * E + b * E + lane] = x2;  // x2_t
        float p = x2 * l3_w[lane];
#pragma unroll
        for (int off = 32; off; off >>= 1) p += __shfl_xor(p, off);
        if (lane == 0) out[B + b] = p + l3_b[0]; // x3_t
    }
}

// ---------------------------------------------------------------------------
extern "C" void kernel_launch(void* const* d_in, const int* in_sizes, int n_in,
                              void* d_out, int out_size, void* d_ws, size_t ws_size,
                              hipStream_t stream) {
    const int*   x            = (const int*)d_in[0];
    const int*   src_his      = (const int*)d_in[1];
    const int*   src_hl       = (const int*)d_in[2];
    const int*   tgt_his      = (const int*)d_in[3];
    const int*   tgt_hl       = (const int*)d_in[4];
    const int*   sample_idx   = (const int*)d_in[5];
    const int*   supp_users   = (const int*)d_in[6];
    const float* src_user_emb = (const float*)d_in[7];
    const float* src_item_emb = (const float*)d_in[8];
    const float* tgt_user_emb = (const float*)d_in[9];
    const float* tgt_item_emb = (const float*)d_in[10];
    const float* W_att_w      = (const float*)d_in[11];
    const float* W_att_b      = (const float*)d_in[12];
    const float* W_agg_w      = (const float*)d_in[13];
    const float* Wq           = (const float*)d_in[14];
    const float* Wk           = (const float*)d_in[15];
    const float* Wv           = (const float*)d_in[16];
    const float* W_out        = (const float*)d_in[17];
    const float* l1_w         = (const float*)d_in[18];
    const float* l1_b         = (const float*)d_in[19];
    const float* l2_w         = (const float*)d_in[20];
    const float* l2_b         = (const float*)d_in[21];
    const float* l3_w         = (const float*)d_in[22];
    const float* l3_b         = (const float*)d_in[23];

    float* ws      = (float*)d_ws;
    float* fea     = ws;                                  // 2*B*E  (src, tgt)
    float* qarr    = fea + 2 * B * E;                     // 2*H*B*E
    float* K_supp  = qarr + 2 * H * B * E;                // H*SUPP*E
    float* garr    = K_supp + H * SUPP * E;               // 2*B*H*E
    float* out     = (float*)d_out;

    encode_kernel<<<dim3(B, 2), 256, 0, stream>>>(
        x, src_his, src_hl, tgt_his, tgt_hl, src_item_emb,
        src_user_emb, tgt_user_emb, W_att_w, W_att_b, W_agg_w, fea);
    ksupp_kernel<<<dim3(1024), 256, 0, stream>>>(
        supp_users, tgt_user_emb, Wk, K_supp);
    q_kernel<<<dim3(256, 2), 256, 0, stream>>>(
        fea, Wq, qarr);
    attn_kernel<<<dim3(B, H, 2), 256, 0, stream>>>(
        sample_idx, K_supp, qarr, Wv, garr);
    final_kernel<<<dim3(B), 256, 0, stream>>>(
        x, tgt_item_emb, garr, garr + B * H * E, W_out,
        l1_w, l1_b, l2_w, l2_b, l3_w, l3_b, out);
}

// Round 4
// 278.613 us; speedup vs baseline: 3.2646x; 1.0917x over previous
//
#include <hip/hip_runtime.h>

// Problem constants (from reference)
constexpr int B    = 1024;
constexpr int L    = 50;
constexpr int S    = 256;
constexpr int H    = 4;
constexpr int E    = 64;
constexpr int HID  = 64;
constexpr int SUPP = 10000;

// Broadcast lane l's value to all lanes of the wave (l must be wave-uniform;
// compiles to v_readlane -> SGPR, usable as the scalar operand of v_fma).
__device__ __forceinline__ float lanebc(float v, int l) {
    return __int_as_float(__builtin_amdgcn_readlane(__float_as_int(v), l));
}

// ---------------------------------------------------------------------------
// Kernel 1: fused pre-work.
//   blockIdx.y in {0,1}: user_fea_encode(call=y) immediately followed by the
//     per-head q projection (wave == head); fea never touches global memory.
//   blockIdx.y == 2:     K_supp[h][j][:] = tgt_user_emb[supp_users[j]] @ Wk[h]
// Reference quirks preserved: src_item_emb for BOTH encode calls; encoder
// softmax has no max-subtract, padded rows contribute exp(0)=1; denom+1e-12.
// ---------------------------------------------------------------------------
__global__ __launch_bounds__(256) void pre_kernel(
    const int* __restrict__ x,            // (B,2)  [:,0]=user_id
    const int* __restrict__ src_his,      // (B,L)
    const int* __restrict__ src_hl,       // (B,)
    const int* __restrict__ tgt_his,      // (B,L)
    const int* __restrict__ tgt_hl,       // (B,)
    const float* __restrict__ item_emb,   // src_item_emb -- always src!
    const float* __restrict__ src_user_emb,
    const float* __restrict__ tgt_user_emb,
    const int* __restrict__ supp_users,   // (SUPP,)
    const float* __restrict__ W_att_w,    // (E,E)
    const float* __restrict__ W_att_b,    // (E,)
    const float* __restrict__ W_agg_w,    // (E,E)
    const float* __restrict__ Wq,         // (H,E,E)
    const float* __restrict__ Wk,         // (H,E,E)
    float* __restrict__ qout,             // (2,H,B,E)
    float* __restrict__ K_supp)           // (H,SUPP,E)
{
    const int tid  = threadIdx.x;
    const int lane = tid & 63;
    const int wave = tid >> 6;

    if (blockIdx.y == 2) {
        // ---------------- ksupp plane ----------------
        const int h = wave;   // wave == head
        float wcol[E];
#pragma unroll
        for (int i = 0; i < E; i++) wcol[i] = Wk[h * E * E + i * E + lane];

#pragma unroll 2
        for (int j = blockIdx.x; j < SUPP; j += gridDim.x) {
            const int u = supp_users[j];
            const float ev = tgt_user_emb[(size_t)u * E + lane];
            float acc = 0.0f;
#pragma unroll
            for (int i = 0; i < E; i++) acc += lanebc(ev, i) * wcol[i];
            K_supp[((size_t)h * SUPP + j) * E + lane] = acc;
        }
        return;
    }

    // ---------------- encode + q plane ----------------
    __shared__ float sHist[L * E];
    __shared__ float sAtt[L];
    __shared__ float sPart[4][E];
    __shared__ float sOut[E];

    const int b    = blockIdx.x;
    const int call = blockIdx.y;

    const int* his = call ? tgt_his : src_his;
    const int* hl  = call ? tgt_hl  : src_hl;
    const float* user_table = call ? tgt_user_emb : src_user_emb;

    float wcol[E];
#pragma unroll
    for (int i = 0; i < E; i++) wcol[i] = W_att_w[i * E + lane];

    const int uid    = x[2 * b];
    const float uv   = user_table[(size_t)uid * E + lane];
    const float bias = W_att_b[lane];
    const int hlen   = hl[b];

    // phase 1: per history row -- gather, stage, key-matmul, att logit
    for (int l = wave; l < L; l += 4) {
        const int it = his[b * L + l];
        const float hv = (l < hlen) ? item_emb[(size_t)it * E + lane] : 0.0f;
        sHist[l * E + lane] = hv;
        float a = bias;
#pragma unroll
        for (int i = 0; i < E; i++) a += lanebc(hv, i) * wcol[i];
        float part = tanhf(a) * uv;
        float hsum = hv;
#pragma unroll
        for (int off = 32; off; off >>= 1) {
            part += __shfl_xor(part, off);
            hsum += __shfl_xor(hsum, off);
        }
        if (lane == 0) sAtt[l] = (hsum == 0.0f) ? 0.0f : part;
    }
    __syncthreads();

    // softmax (no max-subtract; padded rows contribute exp(0)=1)
    if (wave == 0) {
        float v = (lane < L) ? expf(sAtt[lane]) : 0.0f;
        float s = v;
#pragma unroll
        for (int off = 32; off; off >>= 1) s += __shfl_xor(s, off);
        const float denom = s + 1e-12f;
        if (lane < L) sAtt[lane] = v / denom;
    }
    __syncthreads();

    // ctx partials across waves
    float c = 0.0f;
    for (int l = wave; l < L; l += 4) c += sAtt[l] * sHist[l * E + lane];
    sPart[wave][lane] = c;
    __syncthreads();
    if (tid < E) sOut[tid] = sPart[0][tid] + sPart[1][tid] + sPart[2][tid] + sPart[3][tid];
    __syncthreads();

    // agg: fea = ctx @ W_agg, i-range split across waves
    float g = 0.0f;
#pragma unroll
    for (int k = 0; k < 16; k++) {
        const int i = wave * 16 + k;
        g += sOut[i] * W_agg_w[i * E + lane];
    }
    sPart[wave][lane] = g;
    __syncthreads();

    // fea[lane] (every wave computes it; then q projection, wave == head)
    const float fval = sPart[0][lane] + sPart[1][lane] + sPart[2][lane] + sPart[3][lane];
    const float* Wqh = Wq + wave * E * E;
    float qacc = 0.0f;
#pragma unroll
    for (int i = 0; i < E; i++) qacc += lanebc(fval, i) * Wqh[i * E + lane];
    qout[(((call * H) + wave) * B + b) * E + lane] = qacc;
}

// ---------------------------------------------------------------------------
// Kernel 2: attention per (b,h,call).  K tile lives in REGISTERS:
// lane = (rsub = lane>>4, u = lane&15); wave w owns rows [w*64,(w+1)*64);
// kreg[i] = row (s0+4i+rsub), unit u (4 floats).  Logits via in-lane partial
// dot + 4-step shuffle reduce in 16-lane subgroups.  softmax = jax.nn.softmax
// (max-subtracted).  ctx is pure-VALU FMA over the register tile (p via
// bpermute).  ctx uses k itself (reference quirk); g = ctx @ Wv[h].
// ---------------------------------------------------------------------------
__global__ __launch_bounds__(256) void attn_kernel(
    const int* __restrict__ sample_idx,  // (2,H,B,S)
    const float* __restrict__ K_supp,    // (H,SUPP,E)
    const float* __restrict__ qarr,      // (2,H,B,E)
    const float* __restrict__ Wv,        // (H,E,E)
    float* __restrict__ gout)            // (2,B,H*E)
{
    __shared__ float sRed[8];
    __shared__ float sCtx[4][E];
    __shared__ float sC[E];
    __shared__ float sG[4][E];

    const int b    = blockIdx.x;
    const int h    = blockIdx.y;
    const int call = blockIdx.z;
    const int tid  = threadIdx.x;
    const int lane = tid & 63;
    const int wave = tid >> 6;
    const int u    = lane & 15;
    const int rsub = lane >> 4;
    const int s0   = wave * 64;

    const int* idx = sample_idx + (((call * H) + h) * B + b) * S;
    const float* Kh = K_supp + (size_t)h * SUPP * E;
    const float4 qu = *(const float4*)(qarr + ((size_t)(((call * H) + h) * B + b)) * E + 4 * u);

    // ---- gather into registers + logits ----
    float4 kreg[16];
    float mylogit = 0.0f;
#pragma unroll
    for (int i = 0; i < 16; i++) {
        const int j = idx[s0 + 4 * i + rsub];
        kreg[i] = *(const float4*)(Kh + (size_t)j * E + 4 * u);
        float part = kreg[i].x * qu.x + kreg[i].y * qu.y
                   + kreg[i].z * qu.z + kreg[i].w * qu.w;
#pragma unroll
        for (int off = 1; off < 16; off <<= 1) part += __shfl_xor(part, off);
        mylogit = (u == i) ? part : mylogit;   // lane holds row s0 + 4u + rsub
    }

    // ---- block softmax over 256 logits (permutation-invariant) ----
    float m = mylogit;
#pragma unroll
    for (int off = 32; off; off >>= 1) m = fmaxf(m, __shfl_xor(m, off));
    if (lane == 0) sRed[wave] = m;
    __syncthreads();
    const float mx = fmaxf(fmaxf(sRed[0], sRed[1]), fmaxf(sRed[2], sRed[3]));
    const float ex = expf(mylogit - mx);
    float sm = ex;
#pragma unroll
    for (int off = 32; off; off >>= 1) sm += __shfl_xor(sm, off);
    if (lane == 0) sRed[4 + wave] = sm;
    __syncthreads();
    const float denom = sRed[4] + sRed[5] + sRed[6] + sRed[7];
    const float pval = ex / denom;   // weight of row s0 + 4u + rsub

    // ---- ctx: pure-VALU FMA over register tile ----
    // row s0+4i+rsub's weight lives at lane 16*rsub + i
    float4 cacc = make_float4(0.0f, 0.0f, 0.0f, 0.0f);
#pragma unroll
    for (int i = 0; i < 16; i++) {
        const float p = __shfl(pval, (lane & 48) + i);
        cacc.x += p * kreg[i].x;
        cacc.y += p * kreg[i].y;
        cacc.z += p * kreg[i].z;
        cacc.w += p * kreg[i].w;
    }
    // combine across rsub groups (lanes l, l^16, l^32, l^48 share unit u)
#pragma unroll
    for (int off = 16; off <= 32; off <<= 1) {
        cacc.x += __shfl_xor(cacc.x, off);
        cacc.y += __shfl_xor(cacc.y, off);
        cacc.z += __shfl_xor(cacc.z, off);
        cacc.w += __shfl_xor(cacc.w, off);
    }
    if (lane < 16) *(float4*)(&sCtx[wave][u * 4]) = cacc;
    __syncthreads();
    if (wave == 0) {
        sC[lane] = sCtx[0][lane] + sCtx[1][lane] + sCtx[2][lane] + sCtx[3][lane];
    }
    __syncthreads();

    // ---- g = ctx @ Wv[h], c-range split across waves ----
    const float* Wvh = Wv + h * E * E;
    float g = 0.0f;
#pragma unroll
    for (int k = 0; k < 16; k++) {
        const int c = wave * 16 + k;
        g += sC[c] * Wvh[c * E + lane];
    }
    sG[wave][lane] = g;
    __syncthreads();
    if (wave == 0) {
        gout[((size_t)(call * B) + b) * (H * E) + h * E + lane] =
            sG[0][lane] + sG[1][lane] + sG[2][lane] + sG[3][lane];
    }
}

// ---------------------------------------------------------------------------
// Kernel 3: W_out projection + final MLP + all four outputs.
// out layout: [output(B) | x3(B) | out_emb_s(B*E) | x2(B*E)]
// ---------------------------------------------------------------------------
__global__ __launch_bounds__(256) void final_kernel(
    const int* __restrict__ x,             // (B,2) [:,1]=item_id
    const float* __restrict__ tgt_item_emb,
    const float* __restrict__ gsrc,        // (B, H*E) -> user_emb path
    const float* __restrict__ gtgt,        // (B, H*E) -> hybrid path
    const float* __restrict__ W_out,       // (H*E, E)
    const float* __restrict__ l1_w,        // (2E, HID)
    const float* __restrict__ l1_b,        // (HID,)
    const float* __restrict__ l2_w,        // (HID, E)
    const float* __restrict__ l2_b,        // (E,)
    const float* __restrict__ l3_w,        // (E,1)
    const float* __restrict__ l3_b,        // (1,)
    float* __restrict__ out)
{
    __shared__ float sPart[4][E];
    __shared__ float sHyb[E];
    __shared__ float sItem[E];
    __shared__ float sX1[HID];

    const int b    = blockIdx.x;
    const int tid  = threadIdx.x;
    const int lane = tid & 63;
    const int wave = tid >> 6;

    if (tid < E) {
        const int item = x[2 * b + 1];
        sItem[tid] = tgt_item_emb[(size_t)item * E + tid];
    }

    const float* grow = (wave < 2) ? (gsrc + (size_t)b * (H * E))
                                   : (gtgt + (size_t)b * (H * E));
    const int i0 = (wave & 1) * 128;
    float acc = 0.0f;
    for (int i = i0; i < i0 + 128; i++) {
        acc += grow[i] * W_out[i * E + lane];
    }
    sPart[wave][lane] = acc;
    __syncthreads();

    if (wave == 0) {
        const float ue = sPart[0][lane] + sPart[1][lane];
        const float prod = ue * sItem[lane];
        out[2 * B + b * E + lane] = prod;  // out_emb_s
        float s = prod;
#pragma unroll
        for (int off = 32; off; off >>= 1) s += __shfl_xor(s, off);
        if (lane == 0) out[b] = s;         // output
    }
    if (wave == 1) {
        sHyb[lane] = sPart[2][lane] + sPart[3][lane];
    }
    __syncthreads();

    // l1: 128-deep sum split across 4 waves (waves 0,1: hybrid; 2,3: item)
    float a1 = 0.0f;
#pragma unroll
    for (int k = 0; k < 32; k++) {
        const int i = wave * 32 + k;
        const float v = (i < 64) ? sHyb[i] : sItem[i - 64];
        a1 += v * l1_w[i * HID + lane];
    }
    sPart[wave][lane] = a1;
    __syncthreads();

    if (wave == 0) {
        const float a = l1_b[lane] + sPart[0][lane] + sPart[1][lane]
                      + sPart[2][lane] + sPart[3][lane];
        sX1[lane] = tanhf(a);
    }
    __syncthreads();

    if (wave == 0) {
        float a = l2_b[lane];
#pragma unroll
        for (int i = 0; i < HID; i++) a += sX1[i] * l2_w[i * E + lane];
        const float x2 = tanhf(a);
        out[2 * B + B * E + b * E + lane] = x2;  // x2_t
        float p = x2 * l3_w[lane];
#pragma unroll
        for (int off = 32; off; off >>= 1) p += __shfl_xor(p, off);
        if (lane == 0) out[B + b] = p + l3_b[0]; // x3_t
    }
}

// ---------------------------------------------------------------------------
extern "C" void kernel_launch(void* const* d_in, const int* in_sizes, int n_in,
                              void* d_out, int out_size, void* d_ws, size_t ws_size,
                              hipStream_t stream) {
    const int*   x            = (const int*)d_in[0];
    const int*   src_his      = (const int*)d_in[1];
    const int*   src_hl       = (const int*)d_in[2];
    const int*   tgt_his      = (const int*)d_in[3];
    const int*   tgt_hl       = (const int*)d_in[4];
    const int*   sample_idx   = (const int*)d_in[5];
    const int*   supp_users   = (const int*)d_in[6];
    const float* src_user_emb = (const float*)d_in[7];
    const float* src_item_emb = (const float*)d_in[8];
    const float* tgt_user_emb = (const float*)d_in[9];
    const float* tgt_item_emb = (const float*)d_in[10];
    const float* W_att_w      = (const float*)d_in[11];
    const float* W_att_b      = (const float*)d_in[12];
    const float* W_agg_w      = (const float*)d_in[13];
    const float* Wq           = (const float*)d_in[14];
    const float* Wk           = (const float*)d_in[15];
    const float* Wv           = (const float*)d_in[16];
    const float* W_out        = (const float*)d_in[17];
    const float* l1_w         = (const float*)d_in[18];
    const float* l1_b         = (const float*)d_in[19];
    const float* l2_w         = (const float*)d_in[20];
    const float* l2_b         = (const float*)d_in[21];
    const float* l3_w         = (const float*)d_in[22];
    const float* l3_b         = (const float*)d_in[23];

    float* ws      = (float*)d_ws;
    float* qarr    = ws;                                  // 2*H*B*E
    float* K_supp  = qarr + 2 * H * B * E;                // H*SUPP*E
    float* garr    = K_supp + H * SUPP * E;               // 2*B*H*E
    float* out     = (float*)d_out;

    pre_kernel<<<dim3(B, 3), 256, 0, stream>>>(
        x, src_his, src_hl, tgt_his, tgt_hl, src_item_emb,
        src_user_emb, tgt_user_emb, supp_users,
        W_att_w, W_att_b, W_agg_w, Wq, Wk, qarr, K_supp);
    attn_kernel<<<dim3(B, H, 2), 256, 0, stream>>>(
        sample_idx, K_supp, qarr, Wv, garr);
    final_kernel<<<dim3(B), 256, 0, stream>>>(
        x, tgt_item_emb, garr, garr + B * H * E, W_out,
        l1_w, l1_b, l2_w, l2_b, l3_w, l3_b, out);
}